// Round 4
// baseline (1918.415 us; speedup 1.0000x reference)
//
#include <hip/hip_runtime.h>
#include <hip/hip_bf16.h>

// Bidirectional GRU (Keras reset_after=True) + dense classifier.
// B=32, T=160, D=512, H=256, C=6625.
// Round 4: weights-stationary scan. 256 WGs = (dir,b,jg); each WG keeps its
//   rk slice in VGPRs (96 fp32/thread) and exchanges the 256-float h with its
//   3 partner WGs per step via device-scope flags in d_ws. Scan was per-CU
//   L2-BW-bound (re-streaming 384 KB/step/CU); now weight traffic is one-time.

#define B 32
#define T 160
#define D 512
#define H 256
#define C 6625
#define H3 768
#define NT16 416                  // padded 16-col W tiles (415 real + 1 zero)

typedef __attribute__((ext_vector_type(8))) short short8v;
typedef __attribute__((ext_vector_type(4))) float float4v;

__device__ inline unsigned short f2bf(float v) {
    __hip_bfloat16 b = __float2bfloat16(v);
    return *reinterpret_cast<unsigned short*>(&b);
}

// ---------------------------------------------------------------- pack W
// Wp[nt][kc][col][i] = bf16( W[kc*8+i][nt*16+col] ), zero-padded cols.
__global__ __launch_bounds__(256) void pack_W_kernel(
    const float* __restrict__ W, unsigned short* __restrict__ Wp)
{
    const int idx = blockIdx.x * 256 + threadIdx.x;   // < 416*8192
    const int i   = idx & 7;
    const int col = (idx >> 3) & 15;
    const int kc  = (idx >> 7) & 63;
    const int nt  = idx >> 13;
    const int k = kc * 8 + i;
    const int c = nt * 16 + col;
    const float v = (c < C) ? W[k * C + c] : 0.f;
    Wp[idx] = f2bf(v);
}

// ---------------------------------------------------------------- zero flags
__global__ void zero_flags_kernel(int* __restrict__ flags) {
    flags[threadIdx.x] = 0;       // 256 flags, 1 block of 256
}

// ---------------------------------------------------------------- K1: proj
__global__ __launch_bounds__(256) void proj_kernel(
    const float* __restrict__ x,       // [B][T][D]
    const float* __restrict__ kf,      // [D][H3]
    const float* __restrict__ kb,
    const float* __restrict__ bias_f,  // [2][H3]
    const float* __restrict__ bias_b,
    float* __restrict__ xp)            // [2][T][B][H3]
{
    const int ct  = blockIdx.x;
    const int s   = blockIdx.y;
    const int dir = blockIdx.z;
    const int tid = threadIdx.x;
    const int t   = dir ? (T - 1 - s) : s;
    const float* kern = dir ? kb : kf;
    const float* bias = dir ? bias_b : bias_f;

    __shared__ float xs[32 * 512];
    for (int it = 0; it < 16; ++it) {
        int v   = it * 256 + tid;
        int row = v >> 7;
        int k4  = v & 127;
        *(float4*)&xs[(row << 9) + (k4 << 2)] =
            *(const float4*)&x[((row * T + t) << 9) + (k4 << 2)];
    }
    __syncthreads();

    const int col = ct * 256 + tid;
    float acc[32];
#pragma unroll
    for (int r = 0; r < 32; ++r) acc[r] = 0.f;

    for (int k = 0; k < 512; k += 4) {
        float w0 = kern[(k + 0) * H3 + col];
        float w1 = kern[(k + 1) * H3 + col];
        float w2 = kern[(k + 2) * H3 + col];
        float w3 = kern[(k + 3) * H3 + col];
#pragma unroll
        for (int r = 0; r < 32; ++r) {
            float4 xv = *(const float4*)&xs[(r << 9) + k];
            acc[r] += xv.x * w0 + xv.y * w1 + xv.z * w2 + xv.w * w3;
        }
    }

    const float bb = bias[col];
    for (int r = 0; r < 32; ++r)
        xp[((dir * T + s) * B + r) * H3 + col] = acc[r] + bb;
}

// ---------------------------------------------------------------- K2: scan v3
// 256 WGs x 512 threads. WG = (dir, b, jg): owns output slice jg*64..+64 of
// one (dir,b) recurrence. Weights live in VGPRs (3 gates x 32 k x float4/8).
// Thread layout: tid = j*8+kg (j 0..63 output-within-slice, kg 0..7 k-group).
// Per step: FMA partials from LDS h -> shfl_xor reduce over kg -> wave0 does
// gate math, writes h slice to global hbuf, release-flag, spins on partners,
// gathers their slices back into LDS h.
// Block mapping keeps a group's 4 members on one XCD: bid = slot*8 + (g&7),
// slot = (g>>3)*4 + jg.
__global__ __launch_bounds__(512) void gru_scan_v3(
    const float* __restrict__ xp,       // [2][T][B][H3] fp32
    const float* __restrict__ rk_f,     // [H][H3]
    const float* __restrict__ rk_b,
    const float* __restrict__ bias_f,   // [2][H3]
    const float* __restrict__ bias_b,
    __hip_bfloat16* __restrict__ hcatb, // [T][B][2H] bf16
    float* __restrict__ hbuf,           // [2 par][2 dir][32 b][256]
    int* __restrict__ flags)            // [64 g][4 jg]
{
    const int bid  = blockIdx.x;
    const int slot = bid >> 3;
    const int jg   = slot & 3;
    const int g    = ((slot >> 2) << 3) | (bid & 7);   // 0..63
    const int dir  = g >> 5;
    const int b    = g & 31;
    const int tid  = threadIdx.x;
    const int j    = tid >> 3;         // 0..63
    const int kg   = tid & 7;          // 0..7
    const int kbase = kg << 5;         // kg*32

    const float* rk   = dir ? rk_b : rk_f;
    const float* bias = dir ? bias_b : bias_f;

    // ---- load stationary weights into VGPRs (one-time) ----
    const int jcol = jg * 64 + j;      // 0..255
    float4 wz[8], wr[8], wh[8];
#pragma unroll
    for (int q = 0; q < 8; ++q) {
        const int off = (4 * kg + 4 * q) & 31;         // bank stagger
        const float* r0 = rk + (kbase + off) * H3;
        wz[q] = make_float4(r0[jcol],            r0[H3 + jcol],
                            r0[2 * H3 + jcol],   r0[3 * H3 + jcol]);
        wr[q] = make_float4(r0[256 + jcol],          r0[H3 + 256 + jcol],
                            r0[2 * H3 + 256 + jcol], r0[3 * H3 + 256 + jcol]);
        wh[q] = make_float4(r0[512 + jcol],          r0[H3 + 512 + jcol],
                            r0[2 * H3 + 512 + jcol], r0[3 * H3 + 512 + jcol]);
    }

    float rbz = 0.f, rbr = 0.f, rbh = 0.f;
    if (tid < 64) {
        const int c = jg * 64 + tid;
        rbz = bias[H3 + c];
        rbr = bias[H3 + 256 + c];
        rbh = bias[H3 + 512 + c];
    }

    __shared__ float hlds[256];
    __shared__ float sums[3][64];
    if (tid < 256) hlds[tid] = 0.f;
    __syncthreads();

    const int me = (g << 2) | jg;

    for (int s = 0; s < T; ++s) {
        // prefetch this step's x-projection row (L2/HBM latency hides under FMA)
        float xz = 0.f, xr = 0.f, xh = 0.f;
        if (tid < 64) {
            const float* xrow = xp + ((dir * T + s) * B + b) * H3;
            const int c = jg * 64 + tid;
            xz = xrow[c];
            xr = xrow[256 + c];
            xh = xrow[512 + c];
        }

        // ---- partial dots over own k-range, weights in regs, h broadcast ----
        float az = 0.f, ar = 0.f, ah = 0.f;
#pragma unroll
        for (int q = 0; q < 8; ++q) {
            const int off = (4 * kg + 4 * q) & 31;
            float4 h4 = *(const float4*)&hlds[kbase + off];
            az += h4.x * wz[q].x + h4.y * wz[q].y + h4.z * wz[q].z + h4.w * wz[q].w;
            ar += h4.x * wr[q].x + h4.y * wr[q].y + h4.z * wr[q].z + h4.w * wr[q].w;
            ah += h4.x * wh[q].x + h4.y * wh[q].y + h4.z * wh[q].z + h4.w * wh[q].w;
        }

        // ---- reduce across the 8 kg lanes (contiguous in-wave) ----
#pragma unroll
        for (int m = 1; m < 8; m <<= 1) {
            az += __shfl_xor(az, m, 64);
            ar += __shfl_xor(ar, m, 64);
            ah += __shfl_xor(ah, m, 64);
        }
        if (kg == 0) {
            sums[0][j] = az;
            sums[1][j] = ar;
            sums[2][j] = ah;
        }
        __syncthreads();

        // ---- gate math + h exchange (wave0 only) ----
        if (tid < 64) {
            const float sz = sums[0][tid];
            const float sr = sums[1][tid];
            const float sh = sums[2][tid];
            const float z  = 1.f / (1.f + __expf(-(xz + sz + rbz)));
            const float r  = 1.f / (1.f + __expf(-(xr + sr + rbr)));
            const float pre = xh + r * (sh + rbh);
            const float e2  = __expf(2.f * pre);
            const float hh  = 1.f - 2.f / (e2 + 1.f);   // tanh, inf-safe
            const float hn  = z * hlds[jg * 64 + tid] + (1.f - z) * hh;

            hlds[jg * 64 + tid] = hn;                   // own slice for next step

            const int par = (s + 1) & 1;
            float* hb = hbuf + ((((par << 1) | dir) * 32 + b) << 8);
            hb[jg * 64 + tid] = hn;

            const int ta = dir ? (T - 1 - s) : s;
            hcatb[(ta * B + b) * 512 + dir * 256 + jg * 64 + tid] = __float2bfloat16(hn);

            __threadfence();                            // drain wave0 stores, wb L2
            if (tid == 0)
                __hip_atomic_store(&flags[me], s + 1,
                                   __ATOMIC_RELEASE, __HIP_MEMORY_SCOPE_AGENT);

            if (s < T - 1) {
                const int need = s + 1;
                bool ok;
                do {
                    ok = true;
                    if (tid < 3) {
                        const int p = tid + (tid >= jg);
                        ok = __hip_atomic_load(&flags[(g << 2) | p],
                                               __ATOMIC_ACQUIRE,
                                               __HIP_MEMORY_SCOPE_AGENT) >= need;
                    }
                } while (!__all(ok));
                // gather partner slices of h_{s+1}
#pragma unroll
                for (int i = 0; i < 3; ++i) {
                    const int p = i + (i >= jg);
                    hlds[p * 64 + tid] =
                        __hip_atomic_load(&hb[p * 64 + tid],
                                          __ATOMIC_RELAXED, __HIP_MEMORY_SCOPE_AGENT);
                }
            }
        }
        __syncthreads();        // h_{s+1} complete in LDS
    }
}

// ---------------------------------------------------------------- K3: MFMA classifier
__global__ __launch_bounds__(256) void cls_mfma_kernel(
    const __hip_bfloat16* __restrict__ hcatb,
    const unsigned short* __restrict__ Wp,
    const float* __restrict__ bias,
    float* __restrict__ out)
{
    const int lane = threadIdx.x & 63;
    const int wid  = threadIdx.x >> 6;
    const int wm = wid >> 1, wn = wid & 1;
    const int rowBase = blockIdx.x * 64 + wm * 32;
    const int colBase = blockIdx.y * 64 + wn * 32;
    const int lrow = lane & 15;
    const int lk8  = lane >> 4;        // 0..3

    float4v acc[2][2] = {{{0.f,0.f,0.f,0.f},{0.f,0.f,0.f,0.f}},
                         {{0.f,0.f,0.f,0.f},{0.f,0.f,0.f,0.f}}};
    const short* A  = (const short*)hcatb;
    const short* Bp = (const short*)Wp;

    for (int k0 = 0; k0 < 512; k0 += 32) {
        short8v aF[2], bF[2];
#pragma unroll
        for (int mt = 0; mt < 2; ++mt)
            aF[mt] = *(const short8v*)&A[(rowBase + mt * 16 + lrow) * 512 + k0 + lk8 * 8];
#pragma unroll
        for (int ntw = 0; ntw < 2; ++ntw) {
            const int nt16 = blockIdx.y * 4 + wn * 2 + ntw;
            bF[ntw] = *(const short8v*)&Bp[(nt16 * 64 + (k0 >> 3) + lk8) * 128 + lrow * 8];
        }
#pragma unroll
        for (int mt = 0; mt < 2; ++mt)
#pragma unroll
            for (int ntw = 0; ntw < 2; ++ntw)
                acc[mt][ntw] = __builtin_amdgcn_mfma_f32_16x16x32_bf16(
                    aF[mt], bF[ntw], acc[mt][ntw], 0, 0, 0);
    }

    const int orow = (lane >> 4) * 4;   // C/D: col=lane&15, row=(lane>>4)*4+reg
#pragma unroll
    for (int ntw = 0; ntw < 2; ++ntw) {
        const int c = colBase + ntw * 16 + lrow;
        if (c >= C) continue;
        const float bc = bias[c];
#pragma unroll
        for (int mt = 0; mt < 2; ++mt)
#pragma unroll
            for (int v = 0; v < 4; ++v)
                out[(size_t)(rowBase + mt * 16 + orow + v) * C + c] = acc[mt][ntw][v] + bc;
    }
}

// ============================ fallback fp32 path (small ws) ============================
__global__ __launch_bounds__(1024) void gru_scan_f32(
    const float* __restrict__ xp,
    const float* __restrict__ rk_f, const float* __restrict__ rk_b,
    const float* __restrict__ bias_f, const float* __restrict__ bias_b,
    float* __restrict__ hcat)
{
    const int bid = blockIdx.x;
    const int dir = bid >> 5;
    const int b   = bid & 31;
    const int tid = threadIdx.x;
    const int kg  = tid >> 8;
    const int j   = tid & 255;
    const int k0  = kg << 6;
    const float* rk   = dir ? rk_b : rk_f;
    const float* bias = dir ? bias_b : bias_f;
    const float rbz = bias[H3 + j];
    const float rbr = bias[H3 + 256 + j];
    const float rbh = bias[H3 + 512 + j];

    __shared__ float h[256];
    __shared__ float part[3][4][256];
    if (tid < 256) h[tid] = 0.f;
    __syncthreads();

    for (int s = 0; s < T; ++s) {
        const float* xrow = xp + ((dir * T + s) * B + b) * H3;
        float az = 0.f, ar = 0.f, ah = 0.f;
#pragma unroll 4
        for (int k = k0; k < k0 + 64; k += 4) {
            float4 h4 = *(const float4*)&h[k];
            const float* rkp = rk + k * H3 + j;
            az += h4.x * rkp[0];       ar += h4.x * rkp[256];       ah += h4.x * rkp[512];
            az += h4.y * rkp[H3];      ar += h4.y * rkp[H3+256];    ah += h4.y * rkp[H3+512];
            az += h4.z * rkp[2*H3];    ar += h4.z * rkp[2*H3+256];  ah += h4.z * rkp[2*H3+512];
            az += h4.w * rkp[3*H3];    ar += h4.w * rkp[3*H3+256];  ah += h4.w * rkp[3*H3+512];
        }
        part[0][kg][j] = az; part[1][kg][j] = ar; part[2][kg][j] = ah;
        __syncthreads();
        if (tid < 256) {
            const float sz = part[0][0][tid]+part[0][1][tid]+part[0][2][tid]+part[0][3][tid];
            const float sr = part[1][0][tid]+part[1][1][tid]+part[1][2][tid]+part[1][3][tid];
            const float sh = part[2][0][tid]+part[2][1][tid]+part[2][2][tid]+part[2][3][tid];
            const float xz = xrow[tid], xr = xrow[256+tid], xh = xrow[512+tid];
            const float z  = 1.f / (1.f + __expf(-(xz + sz + rbz)));
            const float r  = 1.f / (1.f + __expf(-(xr + sr + rbr)));
            const float pre = xh + r * (sh + rbh);
            const float e2  = __expf(2.f * pre);
            const float hh  = 1.f - 2.f / (e2 + 1.f);
            const float hn  = z * h[tid] + (1.f - z) * hh;
            h[tid] = hn;
            const int ta = dir ? (T - 1 - s) : s;
            hcat[(ta * B + b) * (2 * H) + dir * H + tid] = hn;
        }
        __syncthreads();
    }
}

__global__ __launch_bounds__(256) void cls_f32_kernel(
    const float* __restrict__ hcat, const float* __restrict__ W,
    const float* __restrict__ bias, float* __restrict__ out)
{
    const int bid = blockIdx.x;
    const int ct  = bid / 160;
    const int rt  = bid % 160;
    const int tid = threadIdx.x;
    const int r0  = rt * 32;

    __shared__ float hs[32 * 512];
    for (int it = 0; it < 16; ++it) {
        int v = it * 256 + tid, row = v >> 7, k4 = v & 127;
        *(float4*)&hs[(row << 9) + (k4 << 2)] =
            *(const float4*)&hcat[((r0 + row) << 9) + (k4 << 2)];
    }
    __syncthreads();

    const int c0 = ct * 512 + tid;
    const int c1 = c0 + 256;
    const bool v1 = (c1 < C);
    float acc0[32], acc1[32];
#pragma unroll
    for (int r = 0; r < 32; ++r) { acc0[r] = 0.f; acc1[r] = 0.f; }
    for (int k = 0; k < 512; k += 4) {
        const float* wp = W + k * C;
        float w00 = wp[c0], w01 = wp[C+c0], w02 = wp[2*C+c0], w03 = wp[3*C+c0];
        float w10 = v1 ? wp[c1] : 0.f, w11 = v1 ? wp[C+c1] : 0.f;
        float w12 = v1 ? wp[2*C+c1] : 0.f, w13 = v1 ? wp[3*C+c1] : 0.f;
#pragma unroll
        for (int r = 0; r < 32; ++r) {
            float4 hv = *(const float4*)&hs[(r << 9) + k];
            acc0[r] += hv.x*w00 + hv.y*w01 + hv.z*w02 + hv.w*w03;
            acc1[r] += hv.x*w10 + hv.y*w11 + hv.z*w12 + hv.w*w13;
        }
    }
    const float b0 = bias[c0];
    const float b1 = v1 ? bias[c1] : 0.f;
    for (int r = 0; r < 32; ++r) {
        out[(size_t)(r0+r)*C + c0] = acc0[r] + b0;
        if (v1) out[(size_t)(r0+r)*C + c1] = acc1[r] + b1;
    }
}

// ---------------------------------------------------------------- launch
extern "C" void kernel_launch(void* const* d_in, const int* in_sizes, int n_in,
                              void* d_out, int out_size, void* d_ws, size_t ws_size,
                              hipStream_t stream) {
    const float* x     = (const float*)d_in[0];
    const float* kf    = (const float*)d_in[1];
    const float* rkf   = (const float*)d_in[2];
    const float* biasf = (const float*)d_in[3];
    const float* kb    = (const float*)d_in[4];
    const float* rkb   = (const float*)d_in[5];
    const float* biasb = (const float*)d_in[6];
    const float* W     = (const float*)d_in[7];
    const float* bvec  = (const float*)d_in[8];
    float* out = (float*)d_out;

    const size_t Wp_bytes    = (size_t)NT16 * 8192 * 2;            // 6,815,744
    const size_t hcatb_bytes = (size_t)T * B * 2 * H * 2;          // 5,242,880
    const size_t hbuf_bytes  = (size_t)2 * 2 * 32 * 256 * 4;       //   131,072
    const size_t flag_bytes  = 256 * 4;
    const size_t planA_bytes = Wp_bytes + hcatb_bytes + hbuf_bytes + flag_bytes;

    float* xp = out;   // xp [2][T][B][H3] lives in d_out; dead before cls writes

    if (ws_size >= planA_bytes) {
        char* wsb = (char*)d_ws;
        unsigned short* Wp    = (unsigned short*)wsb;
        __hip_bfloat16* hcatb = (__hip_bfloat16*)(wsb + Wp_bytes);
        float*          hbuf  = (float*)(wsb + Wp_bytes + hcatb_bytes);
        int*            flags = (int*)(wsb + Wp_bytes + hcatb_bytes + hbuf_bytes);

        pack_W_kernel<<<13312, 256, 0, stream>>>(W, Wp);
        zero_flags_kernel<<<1, 256, 0, stream>>>(flags);

        dim3 g1(3, T, 2);
        proj_kernel<<<g1, 256, 0, stream>>>(x, kf, kb, biasf, biasb, xp);

        gru_scan_v3<<<256, 512, 0, stream>>>(xp, rkf, rkb, biasf, biasb,
                                             hcatb, hbuf, flags);

        dim3 g3(80, 104);
        cls_mfma_kernel<<<g3, 256, 0, stream>>>(hcatb, Wp, bvec, out);
    } else {
        // fp32 fallback (round-2 path)
        float* hcat = (float*)d_ws;     // 10.5 MB
        dim3 g1(3, T, 2);
        proj_kernel<<<g1, 256, 0, stream>>>(x, kf, kb, biasf, biasb, xp);
        gru_scan_f32<<<64, 1024, 0, stream>>>(xp, rkf, rkb, biasf, biasb, hcat);
        cls_f32_kernel<<<13 * 160, 256, 0, stream>>>(hcat, W, bvec, out);
    }
}